// Round 1
// baseline (710.933 us; speedup 1.0000x reference)
//
#include <hip/hip_runtime.h>
#include <math.h>

#define B_  4
#define S_  1024
#define H_  768
#define NH_ 12
#define HD_ 64

// ---------------------------------------------------------------------------
// Kernel 1: SE(3) exp map. One thread per sequence position (s < 1024).
// Rt[s*12 + 0..8] = R row-major, Rt[s*12 + 9..11] = t.
// ---------------------------------------------------------------------------
__global__ __launch_bounds__(256)
void k_se3(const float* __restrict__ rp, float* __restrict__ Rt) {
    int s = blockIdx.x * 256 + threadIdx.x;
    if (s >= S_) return;
    float wx = rp[s * 6 + 0], wy = rp[s * 6 + 1], wz = rp[s * 6 + 2];
    float vx = rp[s * 6 + 3], vy = rp[s * 6 + 4], vz = rp[s * 6 + 5];
    float th = sqrtf(wx * wx + wy * wy + wz * wz);
    th = fmaxf(th, 1e-8f);
    float inv = 1.0f / th;
    float ux = wx * inv, uy = wy * inv, uz = wz * inv;
    float K[9] = {0.f, -uz, uy,   uz, 0.f, -ux,   -uy, ux, 0.f};
    float KK[9];
    #pragma unroll
    for (int i = 0; i < 3; ++i)
        #pragma unroll
        for (int j = 0; j < 3; ++j) {
            float acc = 0.f;
            #pragma unroll
            for (int k = 0; k < 3; ++k) acc += K[i * 3 + k] * K[k * 3 + j];
            KK[i * 3 + j] = acc;
        }
    float st = sinf(th), ct = cosf(th);
    float omc = 1.0f - ct;
    float c1 = omc / (th * th);
    float c2 = (th - st) / (th * th * th);
    float R[9], V[9];
    #pragma unroll
    for (int i = 0; i < 9; ++i) {
        float I = (i == 0 || i == 4 || i == 8) ? 1.f : 0.f;
        R[i] = I + st * K[i] + omc * KK[i];
        V[i] = I + c1 * K[i] + c2 * KK[i];
    }
    float tx = V[0] * vx + V[1] * vy + V[2] * vz;
    float ty = V[3] * vx + V[4] * vy + V[5] * vz;
    float tz = V[6] * vx + V[7] * vy + V[8] * vz;
    float* o = Rt + s * 12;
    #pragma unroll
    for (int i = 0; i < 9; ++i) o[i] = R[i];
    o[9] = tx; o[10] = ty; o[11] = tz;
}

// ---------------------------------------------------------------------------
// Kernel 2: apply rotation. Block = 256 threads = 256 3-vectors = one (b,s).
// ---------------------------------------------------------------------------
__global__ __launch_bounds__(256)
void k_rotate(const float* __restrict__ x, const float* __restrict__ Rt,
              float* __restrict__ xr) {
    __shared__ float sR[12];
    int bs = blockIdx.x;            // b*1024 + s
    int s = bs & (S_ - 1);
    if (threadIdx.x < 12) sR[threadIdx.x] = Rt[s * 12 + threadIdx.x];
    __syncthreads();
    int v = threadIdx.x;            // 0..255
    const float* xp = x + (size_t)bs * H_ + v * 3;
    float x0 = xp[0], x1 = xp[1], x2 = xp[2];
    float y0 = sR[0] * x0 + sR[1] * x1 + sR[2] * x2 + sR[9];
    float y1 = sR[3] * x0 + sR[4] * x1 + sR[5] * x2 + sR[10];
    float y2 = sR[6] * x0 + sR[7] * x1 + sR[8] * x2 + sR[11];
    float* yp = xr + (size_t)bs * H_ + v * 3;
    yp[0] = y0; yp[1] = y1; yp[2] = y2;
}

// ---------------------------------------------------------------------------
// Generic fp32 tiled GEMM, C = A . B^T   (both A and B are K-fastest row-major)
// 64x64 tile, BK=16, 256 threads, 4x4 microtile per thread.
// LDS tiles stored transposed [k][m] so inner reads are conflict-free b128.
// MODE 0: plain C row-major (Wo projection -> d_out)
// MODE 1: QKV head layout C[((b*12+head)*1024+s)*64+d], head = blockIdx.y
// MODE 2: scores: per-bh (blockIdx.z), scale 1/8, causal tile skip
// ---------------------------------------------------------------------------
template<int MODE>
__global__ __launch_bounds__(256)
void k_gemm_bt(const float* __restrict__ Abase, const float* __restrict__ Bbase,
               float* __restrict__ Cbase) {
    const int mt = blockIdx.x, nt = blockIdx.y;
    const float* A; const float* Bm;
    int lda, K;
    if constexpr (MODE == 2) {
        if (nt > mt) return;        // uniform per block: safe early exit
        const int bh = blockIdx.z;
        A  = Abase + (size_t)bh * S_ * HD_;
        Bm = Bbase + (size_t)bh * S_ * HD_;
        lda = HD_; K = HD_;
    } else {
        A = Abase; Bm = Bbase; lda = H_; K = H_;
    }
    __shared__ float As[16][64];
    __shared__ float Bs[16][64];
    const int tid = threadIdx.x;
    const int tx = tid & 15, ty = tid >> 4;
    const int lrow = tid >> 2, lk = (tid & 3) * 4;
    const float* ag = A  + (size_t)(mt * 64 + lrow) * lda + lk;
    const float* bg = Bm + (size_t)(nt * 64 + lrow) * lda + lk;
    float acc[4][4] = {};
    for (int kt = 0; kt < K; kt += 16) {
        float4 av = *(const float4*)(ag + kt);
        float4 bv = *(const float4*)(bg + kt);
        __syncthreads();
        As[lk + 0][lrow] = av.x; As[lk + 1][lrow] = av.y;
        As[lk + 2][lrow] = av.z; As[lk + 3][lrow] = av.w;
        Bs[lk + 0][lrow] = bv.x; Bs[lk + 1][lrow] = bv.y;
        Bs[lk + 2][lrow] = bv.z; Bs[lk + 3][lrow] = bv.w;
        __syncthreads();
        #pragma unroll
        for (int kk = 0; kk < 16; ++kk) {
            float4 a4 = *(const float4*)&As[kk][ty * 4];
            float4 b4 = *(const float4*)&Bs[kk][tx * 4];
            float a[4] = {a4.x, a4.y, a4.z, a4.w};
            float b[4] = {b4.x, b4.y, b4.z, b4.w};
            #pragma unroll
            for (int i = 0; i < 4; ++i)
                #pragma unroll
                for (int j = 0; j < 4; ++j)
                    acc[i][j] = fmaf(a[i], b[j], acc[i][j]);
        }
    }
    if constexpr (MODE == 0) {
        #pragma unroll
        for (int i = 0; i < 4; ++i) {
            int r = mt * 64 + ty * 4 + i;
            float4 w = {acc[i][0], acc[i][1], acc[i][2], acc[i][3]};
            *(float4*)&Cbase[(size_t)r * H_ + nt * 64 + tx * 4] = w;
        }
    } else if constexpr (MODE == 1) {
        #pragma unroll
        for (int i = 0; i < 4; ++i) {
            int r = mt * 64 + ty * 4 + i;
            int b = r >> 10, s = r & (S_ - 1);
            float4 w = {acc[i][0], acc[i][1], acc[i][2], acc[i][3]};
            *(float4*)&Cbase[((size_t)(b * NH_ + nt) * S_ + s) * HD_ + tx * 4] = w;
        }
    } else {
        const int bh = blockIdx.z;
        float* C = Cbase + (size_t)bh * S_ * S_;
        #pragma unroll
        for (int i = 0; i < 4; ++i) {
            int r = mt * 64 + ty * 4 + i;
            float4 w = {acc[i][0] * 0.125f, acc[i][1] * 0.125f,
                        acc[i][2] * 0.125f, acc[i][3] * 0.125f};
            *(float4*)&C[(size_t)r * S_ + nt * 64 + tx * 4] = w;
        }
    }
}

// ---------------------------------------------------------------------------
// Kernel: row softmax over raw scores (in-place in attn region of d_out).
// One block (256 threads, 4 waves) per (q, bh) row. Writes full 1024-wide row
// including zeros above the diagonal.
// ---------------------------------------------------------------------------
__global__ __launch_bounds__(256)
void k_softmax(float* __restrict__ attn) {
    const int q  = blockIdx.x;
    const int bh = blockIdx.y;
    float* row = attn + (size_t)bh * S_ * S_ + (size_t)q * S_;
    const int tid = threadIdx.x;
    __shared__ float redm[4];
    __shared__ float redl[4];
    float vals[4];
    float m = -INFINITY;
    #pragma unroll
    for (int i = 0; i < 4; ++i) {
        int j = tid + i * 256;
        vals[i] = (j <= q) ? row[j] : -INFINITY;
        m = fmaxf(m, vals[i]);
    }
    #pragma unroll
    for (int off = 32; off > 0; off >>= 1) m = fmaxf(m, __shfl_xor(m, off));
    if ((tid & 63) == 0) redm[tid >> 6] = m;
    __syncthreads();
    m = fmaxf(fmaxf(redm[0], redm[1]), fmaxf(redm[2], redm[3]));
    float l = 0.f;
    #pragma unroll
    for (int i = 0; i < 4; ++i) {
        int j = tid + i * 256;
        vals[i] = (j <= q) ? __expf(vals[i] - m) : 0.f;
        l += vals[i];
    }
    #pragma unroll
    for (int off = 32; off > 0; off >>= 1) l += __shfl_xor(l, off);
    if ((tid & 63) == 0) redl[tid >> 6] = l;
    __syncthreads();
    l = redl[0] + redl[1] + redl[2] + redl[3];
    float invl = 1.0f / l;
    #pragma unroll
    for (int i = 0; i < 4; ++i) {
        int j = tid + i * 256;
        row[j] = vals[i] * invl;
    }
}

// ---------------------------------------------------------------------------
// Kernel: PV GEMM. ctx[b,s,head*64+d] = sum_j attn[bh,s,j] * v[bh,j,d].
// A = attn (K-fastest), B = v (row-major K x N). Causal: K loop up to row tile.
// ---------------------------------------------------------------------------
__global__ __launch_bounds__(256)
void k_pv(const float* __restrict__ attn, const float* __restrict__ vbuf,
          float* __restrict__ ctx) {
    const int mt = blockIdx.x;
    const int bh = blockIdx.y;
    const float* A  = attn + (size_t)bh * S_ * S_;
    const float* Bp = vbuf + (size_t)bh * S_ * HD_;
    __shared__ float As[16][64];
    __shared__ float Bs[16][64];
    const int tid = threadIdx.x;
    const int tx = tid & 15, ty = tid >> 4;
    const int lrow = tid >> 2, lk = (tid & 3) * 4;
    const int brow = tid >> 4, bc = (tid & 15) * 4;
    const float* ag = A + (size_t)(mt * 64 + lrow) * S_ + lk;
    float acc[4][4] = {};
    const int Klim = (mt + 1) * 64;
    for (int kt = 0; kt < Klim; kt += 16) {
        float4 av = *(const float4*)(ag + kt);
        float4 bv = *(const float4*)(Bp + (size_t)(kt + brow) * HD_ + bc);
        __syncthreads();
        As[lk + 0][lrow] = av.x; As[lk + 1][lrow] = av.y;
        As[lk + 2][lrow] = av.z; As[lk + 3][lrow] = av.w;
        *(float4*)&Bs[brow][bc] = bv;
        __syncthreads();
        #pragma unroll
        for (int kk = 0; kk < 16; ++kk) {
            float4 a4 = *(const float4*)&As[kk][ty * 4];
            float4 b4 = *(const float4*)&Bs[kk][tx * 4];
            float a[4] = {a4.x, a4.y, a4.z, a4.w};
            float b[4] = {b4.x, b4.y, b4.z, b4.w};
            #pragma unroll
            for (int i = 0; i < 4; ++i)
                #pragma unroll
                for (int j = 0; j < 4; ++j)
                    acc[i][j] = fmaf(a[i], b[j], acc[i][j]);
        }
    }
    const int b = bh / NH_, head = bh % NH_;
    #pragma unroll
    for (int i = 0; i < 4; ++i) {
        int s = mt * 64 + ty * 4 + i;
        float4 w = {acc[i][0], acc[i][1], acc[i][2], acc[i][3]};
        *(float4*)&ctx[((size_t)(b * S_ + s)) * H_ + head * HD_ + tx * 4] = w;
    }
}

// ---------------------------------------------------------------------------
extern "C" void kernel_launch(void* const* d_in, const int* in_sizes, int n_in,
                              void* d_out, int out_size, void* d_ws, size_t ws_size,
                              hipStream_t stream) {
    (void)in_sizes; (void)n_in; (void)out_size; (void)ws_size;
    const float* x  = (const float*)d_in[0];
    const float* Wq = (const float*)d_in[1];
    const float* Wk = (const float*)d_in[2];
    const float* Wv = (const float*)d_in[3];
    const float* Wo = (const float*)d_in[4];
    const float* rp = (const float*)d_in[5];

    float* out  = (float*)d_out;
    float* attn = out + (size_t)B_ * S_ * H_;      // 3,145,728 offset

    float* ws = (float*)d_ws;
    float* Rt = ws;                                 // 12,288 floats
    float* xr = ws + 16384;                         // 3,145,728 (reused as ctx)
    float* qb = xr + (size_t)B_ * S_ * H_;
    float* kb = qb + (size_t)B_ * S_ * H_;
    float* vb = kb + (size_t)B_ * S_ * H_;

    k_se3<<<dim3((S_ + 255) / 256), 256, 0, stream>>>(rp, Rt);
    k_rotate<<<dim3(B_ * S_), 256, 0, stream>>>(x, Rt, xr);

    dim3 gProj(B_ * S_ / 64, H_ / 64);              // (64, 12)
    k_gemm_bt<1><<<gProj, 256, 0, stream>>>(xr, Wq, qb);
    k_gemm_bt<1><<<gProj, 256, 0, stream>>>(xr, Wk, kb);
    k_gemm_bt<1><<<gProj, 256, 0, stream>>>(xr, Wv, vb);

    k_gemm_bt<2><<<dim3(S_ / 64, S_ / 64, B_ * NH_), 256, 0, stream>>>(qb, kb, attn);
    k_softmax<<<dim3(S_, B_ * NH_), 256, 0, stream>>>(attn);
    k_pv<<<dim3(S_ / 64, B_ * NH_), 256, 0, stream>>>(attn, vb, xr);  // ctx -> xr

    k_gemm_bt<0><<<gProj, 256, 0, stream>>>(xr, Wo, out);
}

// Round 6
// 427.624 us; speedup vs baseline: 1.6625x; 1.6625x over previous
//
#include <hip/hip_runtime.h>
#include <math.h>

#define S_  1024
#define H_  768
#define NH_ 12
#define HD_ 64
#define BB_ 4

typedef __bf16 bf16x8 __attribute__((ext_vector_type(8)));
typedef float f32x4 __attribute__((ext_vector_type(4)));

// ---- bf16 split helpers (RNE, bit-level) -----------------------------------
__device__ __forceinline__ ushort f2bf(float x) {
    unsigned u = __float_as_uint(x);
    u += 0x7FFF + ((u >> 16) & 1);
    return (ushort)(u >> 16);
}
__device__ __forceinline__ void splitbf(float x, ushort& h, ushort& l) {
    h = f2bf(x);
    float hf = __uint_as_float(((unsigned)h) << 16);
    l = f2bf(x - hf);
}
__device__ __forceinline__ f32x4 mfma16(bf16x8 a, bf16x8 b, f32x4 c) {
    return __builtin_amdgcn_mfma_f32_16x16x32_bf16(a, b, c, 0, 0, 0);
}
// async global->LDS, 16B/lane; LDS dest is wave-uniform base + lane*16
#define GLD16(gp, lp) __builtin_amdgcn_global_load_lds( \
    (const __attribute__((address_space(1))) unsigned int*)(gp), \
    (__attribute__((address_space(3))) unsigned int*)(lp), 16, 0, 0)

// XOR-swizzled frag read from a [rows][64] bf16 tile (128B rows, 8 16B slots).
// LDS(row, s') holds global slot s'^(row&7); reading global slot g uses s'=g^(row&7).
__device__ __forceinline__ bf16x8 fragld(const ushort* tile, int row, int slot) {
    return *(const bf16x8*)((const char*)tile + row * 128 + ((slot ^ (row & 7)) << 4));
}

// ---------------------------------------------------------------------------
// Kernel 1: SE(3) exp map. One thread per sequence position.
// ---------------------------------------------------------------------------
__global__ __launch_bounds__(256)
void k_se3(const float* __restrict__ rp, float* __restrict__ Rt) {
    int s = blockIdx.x * 256 + threadIdx.x;
    if (s >= S_) return;
    float wx = rp[s * 6 + 0], wy = rp[s * 6 + 1], wz = rp[s * 6 + 2];
    float vx = rp[s * 6 + 3], vy = rp[s * 6 + 4], vz = rp[s * 6 + 5];
    float th = sqrtf(wx * wx + wy * wy + wz * wz);
    th = fmaxf(th, 1e-8f);
    float inv = 1.0f / th;
    float ux = wx * inv, uy = wy * inv, uz = wz * inv;
    float K[9] = {0.f, -uz, uy,   uz, 0.f, -ux,   -uy, ux, 0.f};
    float KK[9];
    #pragma unroll
    for (int i = 0; i < 3; ++i)
        #pragma unroll
        for (int j = 0; j < 3; ++j) {
            float acc = 0.f;
            #pragma unroll
            for (int k = 0; k < 3; ++k) acc += K[i * 3 + k] * K[k * 3 + j];
            KK[i * 3 + j] = acc;
        }
    float st = sinf(th), ct = cosf(th);
    float omc = 1.0f - ct;
    float c1 = omc / (th * th);
    float c2 = (th - st) / (th * th * th);
    float R[9], V[9];
    #pragma unroll
    for (int i = 0; i < 9; ++i) {
        float I = (i == 0 || i == 4 || i == 8) ? 1.f : 0.f;
        R[i] = I + st * K[i] + omc * KK[i];
        V[i] = I + c1 * K[i] + c2 * KK[i];
    }
    float tx = V[0] * vx + V[1] * vy + V[2] * vz;
    float ty = V[3] * vx + V[4] * vy + V[5] * vz;
    float tz = V[6] * vx + V[7] * vy + V[8] * vz;
    float* o = Rt + s * 12;
    #pragma unroll
    for (int i = 0; i < 9; ++i) o[i] = R[i];
    o[9] = tx; o[10] = ty; o[11] = tz;
}

// ---------------------------------------------------------------------------
// Kernel 2: rotate + split into bf16 hi/lo. Block = one (b,s), 256 3-vectors.
// ---------------------------------------------------------------------------
__global__ __launch_bounds__(256)
void k_rotate_split(const float* __restrict__ x, const float* __restrict__ Rt,
                    ushort* __restrict__ xrh, ushort* __restrict__ xrl) {
    __shared__ float sR[12];
    int bs = blockIdx.x;
    int s = bs & (S_ - 1);
    if (threadIdx.x < 12) sR[threadIdx.x] = Rt[s * 12 + threadIdx.x];
    __syncthreads();
    int v = threadIdx.x;
    const float* xp = x + (size_t)bs * H_ + v * 3;
    float x0 = xp[0], x1 = xp[1], x2 = xp[2];
    float y0 = sR[0] * x0 + sR[1] * x1 + sR[2] * x2 + sR[9];
    float y1 = sR[3] * x0 + sR[4] * x1 + sR[5] * x2 + sR[10];
    float y2 = sR[6] * x0 + sR[7] * x1 + sR[8] * x2 + sR[11];
    size_t o = (size_t)bs * H_ + v * 3;
    ushort h, lo;
    splitbf(y0, h, lo); xrh[o + 0] = h; xrl[o + 0] = lo;
    splitbf(y1, h, lo); xrh[o + 1] = h; xrl[o + 1] = lo;
    splitbf(y2, h, lo); xrh[o + 2] = h; xrl[o + 2] = lo;
}

// ---------------------------------------------------------------------------
// Kernel 3: split weights. Wq/Wk/Wv -> Wcat (2304x768) hi/lo; Wo -> Woh/Wol.
// ---------------------------------------------------------------------------
__global__ __launch_bounds__(256)
void k_wsplit(const float* __restrict__ Wq, const float* __restrict__ Wk,
              const float* __restrict__ Wv, const float* __restrict__ Wo,
              ushort* __restrict__ Wch, ushort* __restrict__ Wcl,
              ushort* __restrict__ Woh, ushort* __restrict__ Wol) {
    const int wsel = blockIdx.y;
    const float* src = (wsel == 0) ? Wq : (wsel == 1) ? Wk : (wsel == 2) ? Wv : Wo;
    const int e = (blockIdx.x * 256 + threadIdx.x) * 4;
    float4 xv = *(const float4*)(src + e);
    ushort h0, h1, h2, h3, l0, l1, l2, l3;
    splitbf(xv.x, h0, l0); splitbf(xv.y, h1, l1);
    splitbf(xv.z, h2, l2); splitbf(xv.w, h3, l3);
    ushort* dh; ushort* dl; size_t off;
    if (wsel < 3) { dh = Wch; dl = Wcl; off = (size_t)wsel * (H_ * H_) + e; }
    else          { dh = Woh; dl = Wol; off = e; }
    *(ushort4*)(dh + off) = make_ushort4(h0, h1, h2, h3);
    *(ushort4*)(dl + off) = make_ushort4(l0, l1, l2, l3);
}

// ---------------------------------------------------------------------------
// Split-bf16 3-product MFMA GEMM: C = (Ah+Al) . (Bh+Bl)^T, fp32 accum.
// BM=128, BN=NF*32, BK=64, 256 threads (4 waves as 2x2), wave tile 64 x NF*16.
// QKV: A=xr(4096x768), B=Wcat(2304x768), epilogue -> split q/k head layout,
//      V TRANSPOSED [bh][d][s] (so k_pv's B^T-style staging reads P.V not P.V^T).
// OUT: A=ctx(4096x768), B=Wo(768x768),   epilogue -> fp32 d_out.
// ---------------------------------------------------------------------------
template<int NF, bool QKV>
__global__ __launch_bounds__(256, 2)
void k_projsplit(const ushort* __restrict__ Ah, const ushort* __restrict__ Al,
                 const ushort* __restrict__ Bh, const ushort* __restrict__ Bl,
                 ushort* __restrict__ qh, ushort* __restrict__ ql,
                 ushort* __restrict__ kh, ushort* __restrict__ kl,
                 ushort* __restrict__ vh, ushort* __restrict__ vl,
                 float* __restrict__ outp) {
    constexpr int BN = NF * 32;
    __shared__ __align__(16) ushort sAh[128 * 64];
    __shared__ __align__(16) ushort sAl[128 * 64];
    __shared__ __align__(16) ushort sBh[BN * 64];
    __shared__ __align__(16) ushort sBl[BN * 64];
    const int mt = blockIdx.x, nt = blockIdx.y;
    const int tid = threadIdx.x, w = tid >> 6, l = tid & 63;
    const int wr = w >> 1, wc = w & 1;
    const int lrow = l >> 3;                     // row within 8-row group
    const int ksrc = ((l & 7) ^ lrow) * 8;       // pre-swizzled source k-offset
    const ushort* gsrc = (w == 0) ? Ah : (w == 1) ? Al : (w == 2) ? Bh : Bl;
    ushort* tile = (w == 0) ? sAh : (w == 1) ? sAl : (w == 2) ? sBh : sBl;
    const int nrnds = (w < 2) ? 16 : BN / 8;
    const size_t rowbase = (w < 2) ? (size_t)mt * 128 : (size_t)nt * BN;

    f32x4 acc[4][NF];
    #pragma unroll
    for (int i = 0; i < 4; ++i)
        #pragma unroll
        for (int j = 0; j < NF; ++j) acc[i][j] = (f32x4){0.f, 0.f, 0.f, 0.f};

    for (int kt = 0; kt < H_ / 64; ++kt) {
        const int k0 = kt * 64;
        #pragma unroll
        for (int r = 0; r < 16; ++r) {
            if (r < nrnds) {
                const ushort* g = gsrc + (rowbase + r * 8 + lrow) * H_ + k0 + ksrc;
                GLD16(g, (char*)tile + r * 1024);
            }
        }
        __syncthreads();
        #pragma unroll
        for (int ch = 0; ch < 2; ++ch) {
            const int slot = ch * 4 + (l >> 4);
            bf16x8 ah[4], al[4], bh[NF], bl[NF];
            #pragma unroll
            for (int mf = 0; mf < 4; ++mf) {
                int row = wr * 64 + mf * 16 + (l & 15);
                ah[mf] = fragld(sAh, row, slot);
                al[mf] = fragld(sAl, row, slot);
            }
            #pragma unroll
            for (int nf = 0; nf < NF; ++nf) {
                int row = wc * (NF * 16) + nf * 16 + (l & 15);
                bh[nf] = fragld(sBh, row, slot);
                bl[nf] = fragld(sBl, row, slot);
            }
            #pragma unroll
            for (int mf = 0; mf < 4; ++mf)
                #pragma unroll
                for (int nf = 0; nf < NF; ++nf) {
                    acc[mf][nf] = mfma16(ah[mf], bh[nf], acc[mf][nf]);
                    acc[mf][nf] = mfma16(ah[mf], bl[nf], acc[mf][nf]);
                    acc[mf][nf] = mfma16(al[mf], bh[nf], acc[mf][nf]);
                }
        }
        __syncthreads();
    }
    #pragma unroll
    for (int mf = 0; mf < 4; ++mf)
        #pragma unroll
        for (int nf = 0; nf < NF; ++nf)
            #pragma unroll
            for (int q = 0; q < 4; ++q) {
                float val = acc[mf][nf][q];
                int row = mt * 128 + wr * 64 + mf * 16 + (l >> 4) * 4 + q;
                int col = nt * BN + wc * (NF * 16) + nf * 16 + (l & 15);
                if constexpr (QKV) {
                    int which = col / H_;
                    int rem = col - which * H_;
                    int hh = rem >> 6, d = rem & 63;
                    int b = row >> 10, s = row & (S_ - 1);
                    ushort hv, lv; splitbf(val, hv, lv);
                    if (which == 2) {
                        // V transposed: [bh][d][s]  (PV bug fix, round 4)
                        size_t idx = ((size_t)(b * NH_ + hh) * HD_ + d) * S_ + s;
                        vh[idx] = hv; vl[idx] = lv;
                    } else {
                        size_t idx = (((size_t)(b * NH_ + hh) * S_ + s) << 6) + d;
                        ushort* dh = (which == 0) ? qh : kh;
                        ushort* dl = (which == 0) ? ql : kl;
                        dh[idx] = hv; dl[idx] = lv;
                    }
                } else {
                    outp[(size_t)row * H_ + col] = val;
                }
            }
}

// ---------------------------------------------------------------------------
// Scores: per-bh 128x128 tile of q.k^T (split 3-product), K=64 single stage,
// scale 1/8, raw fp32 into attn region. Causal: skip nt>mt blocks.
// ---------------------------------------------------------------------------
__global__ __launch_bounds__(256, 2)
void k_scores(const ushort* __restrict__ qh, const ushort* __restrict__ ql,
              const ushort* __restrict__ kh, const ushort* __restrict__ kl,
              float* __restrict__ attn) {
    const int mt = blockIdx.x, nt = blockIdx.y, bh = blockIdx.z;
    if (nt > mt) return;
    __shared__ __align__(16) ushort sQh[128 * 64];
    __shared__ __align__(16) ushort sQl[128 * 64];
    __shared__ __align__(16) ushort sKh[128 * 64];
    __shared__ __align__(16) ushort sKl[128 * 64];
    const int tid = threadIdx.x, w = tid >> 6, l = tid & 63;
    const int wr = w >> 1, wc = w & 1;
    const int lrow = l >> 3, ksrc = ((l & 7) ^ lrow) * 8;
    const ushort* gsrc = (w == 0) ? qh : (w == 1) ? ql : (w == 2) ? kh : kl;
    ushort* tile = (w == 0) ? sQh : (w == 1) ? sQl : (w == 2) ? sKh : sKl;
    const size_t rowbase = (size_t)bh * S_ + (size_t)((w < 2) ? mt : nt) * 128;
    #pragma unroll
    for (int r = 0; r < 16; ++r) {
        const ushort* g = gsrc + (rowbase + r * 8 + lrow) * HD_ + ksrc;
        GLD16(g, (char*)tile + r * 1024);
    }
    f32x4 acc[4][4];
    #pragma unroll
    for (int i = 0; i < 4; ++i)
        #pragma unroll
        for (int j = 0; j < 4; ++j) acc[i][j] = (f32x4){0.f, 0.f, 0.f, 0.f};
    __syncthreads();
    #pragma unroll
    for (int ch = 0; ch < 2; ++ch) {
        const int slot = ch * 4 + (l >> 4);
        bf16x8 ah[4], al[4], bh4[4], bl4[4];
        #pragma unroll
        for (int mf = 0; mf < 4; ++mf) {
            int row = wr * 64 + mf * 16 + (l & 15);
            ah[mf] = fragld(sQh, row, slot);
            al[mf] = fragld(sQl, row, slot);
        }
        #pragma unroll
        for (int nf = 0; nf < 4; ++nf) {
            int row = wc * 64 + nf * 16 + (l & 15);
            bh4[nf] = fragld(sKh, row, slot);
            bl4[nf] = fragld(sKl, row, slot);
        }
        #pragma unroll
        for (int mf = 0; mf < 4; ++mf)
            #pragma unroll
            for (int nf = 0; nf < 4; ++nf) {
                acc[mf][nf] = mfma16(ah[mf], bh4[nf], acc[mf][nf]);
                acc[mf][nf] = mfma16(ah[mf], bl4[nf], acc[mf][nf]);
                acc[mf][nf] = mfma16(al[mf], bh4[nf], acc[mf][nf]);
            }
    }
    #pragma unroll
    for (int mf = 0; mf < 4; ++mf)
        #pragma unroll
        for (int nf = 0; nf < 4; ++nf)
            #pragma unroll
            for (int q = 0; q < 4; ++q) {
                int row = mt * 128 + wr * 64 + mf * 16 + (l >> 4) * 4 + q;
                int col = nt * 128 + wc * 64 + nf * 16 + (l & 15);
                attn[((size_t)bh << 20) + ((size_t)row << 10) + col] =
                    acc[mf][nf][q] * 0.125f;
            }
}

// ---------------------------------------------------------------------------
// Row softmax, in place over the attn region. One block per (q,bh) row.
// ---------------------------------------------------------------------------
__global__ __launch_bounds__(256)
void k_softmax(float* __restrict__ attn) {
    const int q  = blockIdx.x;
    const int bh = blockIdx.y;
    float* row = attn + (size_t)bh * S_ * S_ + (size_t)q * S_;
    const int tid = threadIdx.x;
    __shared__ float redm[4];
    __shared__ float redl[4];
    float vals[4];
    float m = -INFINITY;
    #pragma unroll
    for (int i = 0; i < 4; ++i) {
        int j = tid + i * 256;
        vals[i] = (j <= q) ? row[j] : -INFINITY;
        m = fmaxf(m, vals[i]);
    }
    #pragma unroll
    for (int off = 32; off > 0; off >>= 1) m = fmaxf(m, __shfl_xor(m, off));
    if ((tid & 63) == 0) redm[tid >> 6] = m;
    __syncthreads();
    m = fmaxf(fmaxf(redm[0], redm[1]), fmaxf(redm[2], redm[3]));
    float lsum = 0.f;
    #pragma unroll
    for (int i = 0; i < 4; ++i) {
        int j = tid + i * 256;
        vals[i] = (j <= q) ? __expf(vals[i] - m) : 0.f;
        lsum += vals[i];
    }
    #pragma unroll
    for (int off = 32; off > 0; off >>= 1) lsum += __shfl_xor(lsum, off);
    if ((tid & 63) == 0) redl[tid >> 6] = lsum;
    __syncthreads();
    lsum = redl[0] + redl[1] + redl[2] + redl[3];
    float invl = 1.0f / lsum;
    #pragma unroll
    for (int i = 0; i < 4; ++i) {
        int j = tid + i * 256;
        row[j] = vals[i] * invl;
    }
}

// ---------------------------------------------------------------------------
// PV: ctx = attn . v  (split 3-product). BM=128, BN=64, BK=64, causal K-limit.
// attn fp32 reg-staged + split into LDS (swizzled writes); v^T hi/lo gload-staged
// (v stored [bh][d][s] so LDS tiles are [n=d][k=j], the B^T layout fragld needs).
// ---------------------------------------------------------------------------
__global__ __launch_bounds__(256, 2)
void k_pv(const float* __restrict__ attn, const ushort* __restrict__ vh,
          const ushort* __restrict__ vl,
          ushort* __restrict__ ctxh, ushort* __restrict__ ctxl) {
    const int mt = blockIdx.x, bh = blockIdx.y;
    __shared__ __align__(16) ushort sPh[128 * 64];
    __shared__ __align__(16) ushort sPl[128 * 64];
    __shared__ __align__(16) ushort sVh[64 * 64];
    __shared__ __align__(16) ushort sVl[64 * 64];
    const int tid = threadIdx.x, w = tid >> 6, l = tid & 63;
    const int wr = w >> 1, wc = w & 1;
    const int lrow = l >> 3, ksrc = ((l & 7) ^ lrow) * 8;
    f32x4 acc[4][2];
    #pragma unroll
    for (int i = 0; i < 4; ++i)
        #pragma unroll
        for (int j = 0; j < 2; ++j) acc[i][j] = (f32x4){0.f, 0.f, 0.f, 0.f};
    const int nsteps = (mt + 1) * 2;
    for (int kt = 0; kt < nsteps; ++kt) {
        __syncthreads();        // protect previous iteration's LDS reads
        #pragma unroll
        for (int j = 0; j < 8; ++j) {
            int idx = j * 256 + tid;           // 0..2047
            int row = idx >> 4, f4 = idx & 15;
            const float* src = attn + ((size_t)bh << 20)
                             + (size_t)(mt * 128 + row) * S_ + kt * 64 + f4 * 4;
            float4 xv = *(const float4*)src;
            ushort h0, h1, h2, h3, l0, l1, l2, l3;
            splitbf(xv.x, h0, l0); splitbf(xv.y, h1, l1);
            splitbf(xv.z, h2, l2); splitbf(xv.w, h3, l3);
            int addr = row * 128 + ((((f4 >> 1) ^ (row & 7))) << 4) + ((f4 & 1) << 3);
            *(ushort4*)((char*)sPh + addr) = make_ushort4(h0, h1, h2, h3);
            *(ushort4*)((char*)sPl + addr) = make_ushort4(l0, l1, l2, l3);
        }
        if (w < 2) {
            // v^T rows are d (0..63), cols are j; stage the 64-wide j-slice at kt*64
            const ushort* gv = (w == 0) ? vh : vl;
            ushort* tv = (w == 0) ? sVh : sVl;
            #pragma unroll
            for (int r = 0; r < 8; ++r) {
                const ushort* g = gv + ((size_t)bh * HD_ + r * 8 + lrow) * S_
                                + kt * 64 + ksrc;
                GLD16(g, (char*)tv + r * 1024);
            }
        }
        __syncthreads();
        #pragma unroll
        for (int ch = 0; ch < 2; ++ch) {
            const int slot = ch * 4 + (l >> 4);
            bf16x8 ph[4], pl[4], bvh[2], bvl[2];
            #pragma unroll
            for (int mf = 0; mf < 4; ++mf) {
                int row = wr * 64 + mf * 16 + (l & 15);
                ph[mf] = fragld(sPh, row, slot);
                pl[mf] = fragld(sPl, row, slot);
            }
            #pragma unroll
            for (int nf = 0; nf < 2; ++nf) {
                int row = wc * 32 + nf * 16 + (l & 15);
                bvh[nf] = fragld(sVh, row, slot);
                bvl[nf] = fragld(sVl, row, slot);
            }
            #pragma unroll
            for (int mf = 0; mf < 4; ++mf)
                #pragma unroll
                for (int nf = 0; nf < 2; ++nf) {
                    acc[mf][nf] = mfma16(ph[mf], bvh[nf], acc[mf][nf]);
                    acc[mf][nf] = mfma16(ph[mf], bvl[nf], acc[mf][nf]);
                    acc[mf][nf] = mfma16(pl[mf], bvh[nf], acc[mf][nf]);
                }
        }
    }
    const int b = bh / NH_, head = bh - b * NH_;
    #pragma unroll
    for (int mf = 0; mf < 4; ++mf)
        #pragma unroll
        for (int nf = 0; nf < 2; ++nf)
            #pragma unroll
            for (int q = 0; q < 4; ++q) {
                int s = mt * 128 + wr * 64 + mf * 16 + (l >> 4) * 4 + q;
                int d = wc * 32 + nf * 16 + (l & 15);
                size_t idx = ((size_t)(b * S_ + s)) * H_ + head * HD_ + d;
                ushort hv, lv; splitbf(acc[mf][nf][q], hv, lv);
                ctxh[idx] = hv; ctxl[idx] = lv;
            }
}

// ---------------------------------------------------------------------------
extern "C" void kernel_launch(void* const* d_in, const int* in_sizes, int n_in,
                              void* d_out, int out_size, void* d_ws, size_t ws_size,
                              hipStream_t stream) {
    (void)in_sizes; (void)n_in; (void)out_size; (void)ws_size;
    const float* x  = (const float*)d_in[0];
    const float* Wq = (const float*)d_in[1];
    const float* Wk = (const float*)d_in[2];
    const float* Wv = (const float*)d_in[3];
    const float* Wo = (const float*)d_in[4];
    const float* rp = (const float*)d_in[5];

    float* out  = (float*)d_out;
    float* attn = out + (size_t)BB_ * S_ * H_;

    char* p = (char*)d_ws;
    auto alloc = [&](size_t bytes) { char* r = p; p += (bytes + 255) & ~(size_t)255; return r; };
    const size_t NE = (size_t)BB_ * S_ * H_;          // 3,145,728
    float*  Rt   = (float*) alloc(S_ * 12 * 4);
    ushort* xrh  = (ushort*)alloc(NE * 2);            // reused as ctxh after QKV proj
    ushort* xrl  = (ushort*)alloc(NE * 2);            // reused as ctxl
    ushort* Wch  = (ushort*)alloc((size_t)3 * H_ * H_ * 2);
    ushort* Wcl  = (ushort*)alloc((size_t)3 * H_ * H_ * 2);
    ushort* Woh  = (ushort*)alloc((size_t)H_ * H_ * 2);
    ushort* Wol  = (ushort*)alloc((size_t)H_ * H_ * 2);
    ushort* qh   = (ushort*)alloc(NE * 2);
    ushort* ql   = (ushort*)alloc(NE * 2);
    ushort* kh   = (ushort*)alloc(NE * 2);
    ushort* kl   = (ushort*)alloc(NE * 2);
    ushort* vh   = (ushort*)alloc(NE * 2);            // stored transposed [bh][d][s]
    ushort* vl   = (ushort*)alloc(NE * 2);
    ushort* ctxh = xrh;     // xr dead after QKV projection (stream-ordered)
    ushort* ctxl = xrl;

    k_se3<<<dim3(4), 256, 0, stream>>>(rp, Rt);
    k_rotate_split<<<dim3(BB_ * S_), 256, 0, stream>>>(x, Rt, xrh, xrl);
    k_wsplit<<<dim3(576, 4), 256, 0, stream>>>(Wq, Wk, Wv, Wo, Wch, Wcl, Woh, Wol);

    // q,k,v projections fused: N = 2304
    k_projsplit<4, true><<<dim3(32, 18), 256, 0, stream>>>(
        xrh, xrl, Wch, Wcl, qh, ql, kh, kl, vh, vl, nullptr);

    k_scores<<<dim3(8, 8, BB_ * NH_), 256, 0, stream>>>(qh, ql, kh, kl, attn);
    k_softmax<<<dim3(S_, BB_ * NH_), 256, 0, stream>>>(attn);
    k_pv<<<dim3(8, BB_ * NH_), 256, 0, stream>>>(attn, vh, vl, ctxh, ctxl);

    // output projection: N = 768
    k_projsplit<2, false><<<dim3(32, 12), 256, 0, stream>>>(
        ctxh, ctxl, Woh, Wol, nullptr, nullptr, nullptr, nullptr, nullptr, nullptr, out);
}

// Round 7
// 412.237 us; speedup vs baseline: 1.7246x; 1.0373x over previous
//
#include <hip/hip_runtime.h>
#include <math.h>

#define S_  1024
#define H_  768
#define NH_ 12
#define HD_ 64
#define BB_ 4

typedef __bf16 bf16x8 __attribute__((ext_vector_type(8)));
typedef float f32x4 __attribute__((ext_vector_type(4)));

// ---- bf16 helpers (RNE, bit-level) -----------------------------------------
__device__ __forceinline__ ushort f2bf(float x) {
    unsigned u = __float_as_uint(x);
    u += 0x7FFF + ((u >> 16) & 1);
    return (ushort)(u >> 16);
}
__device__ __forceinline__ void splitbf(float x, ushort& h, ushort& l) {
    h = f2bf(x);
    float hf = __uint_as_float(((unsigned)h) << 16);
    l = f2bf(x - hf);
}
__device__ __forceinline__ f32x4 mfma16(bf16x8 a, bf16x8 b, f32x4 c) {
    return __builtin_amdgcn_mfma_f32_16x16x32_bf16(a, b, c, 0, 0, 0);
}
#define GLD16(gp, lp) __builtin_amdgcn_global_load_lds( \
    (const __attribute__((address_space(1))) unsigned int*)(gp), \
    (__attribute__((address_space(3))) unsigned int*)(lp), 16, 0, 0)

// XOR-swizzled frag read from a [rows][64] bf16 tile (128B rows, 8 16B slots).
__device__ __forceinline__ bf16x8 fragld(const ushort* tile, int row, int slot) {
    return *(const bf16x8*)((const char*)tile + row * 128 + ((slot ^ (row & 7)) << 4));
}

// ---------------------------------------------------------------------------
// Kernel 1: SE(3) exp map.
// ---------------------------------------------------------------------------
__global__ __launch_bounds__(256)
void k_se3(const float* __restrict__ rp, float* __restrict__ Rt) {
    int s = blockIdx.x * 256 + threadIdx.x;
    if (s >= S_) return;
    float wx = rp[s * 6 + 0], wy = rp[s * 6 + 1], wz = rp[s * 6 + 2];
    float vx = rp[s * 6 + 3], vy = rp[s * 6 + 4], vz = rp[s * 6 + 5];
    float th = sqrtf(wx * wx + wy * wy + wz * wz);
    th = fmaxf(th, 1e-8f);
    float inv = 1.0f / th;
    float ux = wx * inv, uy = wy * inv, uz = wz * inv;
    float K[9] = {0.f, -uz, uy,   uz, 0.f, -ux,   -uy, ux, 0.f};
    float KK[9];
    #pragma unroll
    for (int i = 0; i < 3; ++i)
        #pragma unroll
        for (int j = 0; j < 3; ++j) {
            float acc = 0.f;
            #pragma unroll
            for (int k = 0; k < 3; ++k) acc += K[i * 3 + k] * K[k * 3 + j];
            KK[i * 3 + j] = acc;
        }
    float st = sinf(th), ct = cosf(th);
    float omc = 1.0f - ct;
    float c1 = omc / (th * th);
    float c2 = (th - st) / (th * th * th);
    float R[9], V[9];
    #pragma unroll
    for (int i = 0; i < 9; ++i) {
        float I = (i == 0 || i == 4 || i == 8) ? 1.f : 0.f;
        R[i] = I + st * K[i] + omc * KK[i];
        V[i] = I + c1 * K[i] + c2 * KK[i];
    }
    float tx = V[0] * vx + V[1] * vy + V[2] * vz;
    float ty = V[3] * vx + V[4] * vy + V[5] * vz;
    float tz = V[6] * vx + V[7] * vy + V[8] * vz;
    float* o = Rt + s * 12;
    #pragma unroll
    for (int i = 0; i < 9; ++i) o[i] = R[i];
    o[9] = tx; o[10] = ty; o[11] = tz;
}

// ---------------------------------------------------------------------------
// Kernel 2: rotate + split x into bf16 hi/lo (A-side of QKV proj: both used).
// ---------------------------------------------------------------------------
__global__ __launch_bounds__(256)
void k_rotate_split(const float* __restrict__ x, const float* __restrict__ Rt,
                    ushort* __restrict__ xrh, ushort* __restrict__ xrl) {
    __shared__ float sR[12];
    int bs = blockIdx.x;
    int s = bs & (S_ - 1);
    if (threadIdx.x < 12) sR[threadIdx.x] = Rt[s * 12 + threadIdx.x];
    __syncthreads();
    int v = threadIdx.x;
    const float* xp = x + (size_t)bs * H_ + v * 3;
    float x0 = xp[0], x1 = xp[1], x2 = xp[2];
    float y0 = sR[0] * x0 + sR[1] * x1 + sR[2] * x2 + sR[9];
    float y1 = sR[3] * x0 + sR[4] * x1 + sR[5] * x2 + sR[10];
    float y2 = sR[6] * x0 + sR[7] * x1 + sR[8] * x2 + sR[11];
    size_t o = (size_t)bs * H_ + v * 3;
    ushort h, lo;
    splitbf(y0, h, lo); xrh[o + 0] = h; xrl[o + 0] = lo;
    splitbf(y1, h, lo); xrh[o + 1] = h; xrl[o + 1] = lo;
    splitbf(y2, h, lo); xrh[o + 2] = h; xrl[o + 2] = lo;
}

// ---------------------------------------------------------------------------
// Kernel 3: round weights to bf16 HI only (B-side lo dropped: 2-product split).
// Wq/Wk/Wv -> Wch (2304x768); Wo -> Woh.
// ---------------------------------------------------------------------------
__global__ __launch_bounds__(256)
void k_wsplit(const float* __restrict__ Wq, const float* __restrict__ Wk,
              const float* __restrict__ Wv, const float* __restrict__ Wo,
              ushort* __restrict__ Wch, ushort* __restrict__ Woh) {
    const int wsel = blockIdx.y;
    const float* src = (wsel == 0) ? Wq : (wsel == 1) ? Wk : (wsel == 2) ? Wv : Wo;
    const int e = (blockIdx.x * 256 + threadIdx.x) * 4;
    float4 xv = *(const float4*)(src + e);
    ushort4 hv = make_ushort4(f2bf(xv.x), f2bf(xv.y), f2bf(xv.z), f2bf(xv.w));
    if (wsel < 3) *(ushort4*)(Wch + (size_t)wsel * (H_ * H_) + e) = hv;
    else          *(ushort4*)(Woh + e) = hv;
}

// ---------------------------------------------------------------------------
// 2-product split GEMM: C = (Ah+Al) . Bh^T, fp32 accum.
// BM=128, BN=NF*32, BK=64, 4 waves (2x2), staging rebalanced across all waves.
// QKV: epilogue -> q split hi/lo, k hi, V TRANSPOSED [bh][d][s] hi.
// OUT: epilogue -> fp32 d_out.
// ---------------------------------------------------------------------------
template<int NF, bool QKV>
__global__ __launch_bounds__(256, 2)
void k_proj2(const ushort* __restrict__ Ah, const ushort* __restrict__ Al,
             const ushort* __restrict__ Bh,
             ushort* __restrict__ qh, ushort* __restrict__ ql,
             ushort* __restrict__ kh, ushort* __restrict__ vh,
             float* __restrict__ outp) {
    constexpr int BN = NF * 32;
    constexpr int TOT = 32 + BN / 8;           // staging rounds (A-hi, A-lo, B-hi)
    __shared__ __align__(16) ushort sAh[128 * 64];
    __shared__ __align__(16) ushort sAl[128 * 64];
    __shared__ __align__(16) ushort sBh[BN * 64];
    const int mt = blockIdx.x, nt = blockIdx.y;
    const int tid = threadIdx.x, w = tid >> 6, l = tid & 63;
    const int wr = w >> 1, wc = w & 1;
    const int lrow = l >> 3;
    const int ksrc = ((l & 7) ^ lrow) * 8;     // pre-swizzled source k-offset

    f32x4 acc[4][NF];
    #pragma unroll
    for (int i = 0; i < 4; ++i)
        #pragma unroll
        for (int j = 0; j < NF; ++j) acc[i][j] = (f32x4){0.f, 0.f, 0.f, 0.f};

    for (int kt = 0; kt < H_ / 64; ++kt) {
        const int k0 = kt * 64;
        for (int rr = w; rr < TOT; rr += 4) {
            int t = (rr < 16) ? 0 : (rr < 32) ? 1 : 2;
            int r = rr - ((rr < 16) ? 0 : (rr < 32) ? 16 : 32);
            const ushort* src = (t == 0) ? Ah : (t == 1) ? Al : Bh;
            size_t rowb = (t < 2) ? (size_t)mt * 128 : (size_t)nt * BN;
            const ushort* g = src + (rowb + r * 8 + lrow) * H_ + k0 + ksrc;
            ushort* dstt = (t == 0) ? sAh : (t == 1) ? sAl : sBh;
            GLD16(g, dstt + r * 512);
        }
        __syncthreads();
        #pragma unroll
        for (int ch = 0; ch < 2; ++ch) {
            const int slot = ch * 4 + (l >> 4);
            bf16x8 ah[4], al[4], bh[NF];
            #pragma unroll
            for (int mf = 0; mf < 4; ++mf) {
                int row = wr * 64 + mf * 16 + (l & 15);
                ah[mf] = fragld(sAh, row, slot);
                al[mf] = fragld(sAl, row, slot);
            }
            #pragma unroll
            for (int nf = 0; nf < NF; ++nf)
                bh[nf] = fragld(sBh, wc * (NF * 16) + nf * 16 + (l & 15), slot);
            #pragma unroll
            for (int mf = 0; mf < 4; ++mf)
                #pragma unroll
                for (int nf = 0; nf < NF; ++nf) {
                    acc[mf][nf] = mfma16(ah[mf], bh[nf], acc[mf][nf]);
                    acc[mf][nf] = mfma16(al[mf], bh[nf], acc[mf][nf]);
                }
        }
        __syncthreads();
    }
    #pragma unroll
    for (int mf = 0; mf < 4; ++mf)
        #pragma unroll
        for (int nf = 0; nf < NF; ++nf)
            #pragma unroll
            for (int q = 0; q < 4; ++q) {
                float val = acc[mf][nf][q];
                int row = mt * 128 + wr * 64 + mf * 16 + (l >> 4) * 4 + q;
                int col = nt * BN + wc * (NF * 16) + nf * 16 + (l & 15);
                if constexpr (QKV) {
                    int which = col / H_;
                    int rem = col - which * H_;
                    int hh = rem >> 6, d = rem & 63;
                    int b = row >> 10, s = row & (S_ - 1);
                    if (which == 2) {
                        // V transposed [bh][d][s], hi only
                        vh[((size_t)(b * NH_ + hh) * HD_ + d) * S_ + s] = f2bf(val);
                    } else if (which == 1) {
                        kh[(((size_t)(b * NH_ + hh) * S_ + s) << 6) + d] = f2bf(val);
                    } else {
                        size_t idx = (((size_t)(b * NH_ + hh) * S_ + s) << 6) + d;
                        ushort hv, lv; splitbf(val, hv, lv);
                        qh[idx] = hv; ql[idx] = lv;
                    }
                } else {
                    outp[(size_t)row * H_ + col] = val;
                }
            }
}

// ---------------------------------------------------------------------------
// Scores: S = (qh+ql).kh^T per bh 128x128 tile, scale 1/8, raw fp32 to attn.
// ---------------------------------------------------------------------------
__global__ __launch_bounds__(256, 2)
void k_scores(const ushort* __restrict__ qh, const ushort* __restrict__ ql,
              const ushort* __restrict__ kh, float* __restrict__ attn) {
    const int mt = blockIdx.x, nt = blockIdx.y, bh = blockIdx.z;
    if (nt > mt) return;
    __shared__ __align__(16) ushort sQh[128 * 64];
    __shared__ __align__(16) ushort sQl[128 * 64];
    __shared__ __align__(16) ushort sKh[128 * 64];
    const int tid = threadIdx.x, w = tid >> 6, l = tid & 63;
    const int wr = w >> 1, wc = w & 1;
    const int lrow = l >> 3, ksrc = ((l & 7) ^ lrow) * 8;
    for (int rr = w; rr < 48; rr += 4) {
        int t = (rr < 16) ? 0 : (rr < 32) ? 1 : 2;
        int r = rr - ((rr < 16) ? 0 : (rr < 32) ? 16 : 32);
        const ushort* src = (t == 0) ? qh : (t == 1) ? ql : kh;
        size_t rowb = (size_t)bh * S_ + (size_t)((t < 2) ? mt : nt) * 128;
        const ushort* g = src + (rowb + r * 8 + lrow) * HD_ + ksrc;
        ushort* dstt = (t == 0) ? sQh : (t == 1) ? sQl : sKh;
        GLD16(g, dstt + r * 512);
    }
    f32x4 acc[4][4];
    #pragma unroll
    for (int i = 0; i < 4; ++i)
        #pragma unroll
        for (int j = 0; j < 4; ++j) acc[i][j] = (f32x4){0.f, 0.f, 0.f, 0.f};
    __syncthreads();
    #pragma unroll
    for (int ch = 0; ch < 2; ++ch) {
        const int slot = ch * 4 + (l >> 4);
        bf16x8 ah[4], al[4], bh4[4];
        #pragma unroll
        for (int mf = 0; mf < 4; ++mf) {
            int row = wr * 64 + mf * 16 + (l & 15);
            ah[mf] = fragld(sQh, row, slot);
            al[mf] = fragld(sQl, row, slot);
        }
        #pragma unroll
        for (int nf = 0; nf < 4; ++nf)
            bh4[nf] = fragld(sKh, wc * 64 + nf * 16 + (l & 15), slot);
        #pragma unroll
        for (int mf = 0; mf < 4; ++mf)
            #pragma unroll
            for (int nf = 0; nf < 4; ++nf) {
                acc[mf][nf] = mfma16(ah[mf], bh4[nf], acc[mf][nf]);
                acc[mf][nf] = mfma16(al[mf], bh4[nf], acc[mf][nf]);
            }
    }
    #pragma unroll
    for (int mf = 0; mf < 4; ++mf)
        #pragma unroll
        for (int nf = 0; nf < 4; ++nf)
            #pragma unroll
            for (int q = 0; q < 4; ++q) {
                int row = mt * 128 + wr * 64 + mf * 16 + (l >> 4) * 4 + q;
                int col = nt * 128 + wc * 64 + nf * 16 + (l & 15);
                attn[((size_t)bh << 20) + ((size_t)row << 10) + col] =
                    acc[mf][nf][q] * 0.125f;
            }
}

// ---------------------------------------------------------------------------
// Row softmax, float4-vectorized. One block per (q,bh) row; thread owns 4 cols.
// ---------------------------------------------------------------------------
__global__ __launch_bounds__(256)
void k_softmax(float* __restrict__ attn) {
    const int q  = blockIdx.x;
    const int bh = blockIdx.y;
    float* row = attn + ((size_t)bh << 20) + ((size_t)q << 10);
    const int tid = threadIdx.x;
    const int j0 = tid * 4;
    __shared__ float redm[4];
    __shared__ float redl[4];
    float4 v = *(const float4*)(row + j0);
    float x0 = (j0 + 0 <= q) ? v.x : -INFINITY;
    float x1 = (j0 + 1 <= q) ? v.y : -INFINITY;
    float x2 = (j0 + 2 <= q) ? v.z : -INFINITY;
    float x3 = (j0 + 3 <= q) ? v.w : -INFINITY;
    float m = fmaxf(fmaxf(x0, x1), fmaxf(x2, x3));
    #pragma unroll
    for (int off = 32; off > 0; off >>= 1) m = fmaxf(m, __shfl_xor(m, off));
    if ((tid & 63) == 0) redm[tid >> 6] = m;
    __syncthreads();
    m = fmaxf(fmaxf(redm[0], redm[1]), fmaxf(redm[2], redm[3]));
    float e0 = __expf(x0 - m), e1 = __expf(x1 - m);
    float e2 = __expf(x2 - m), e3 = __expf(x3 - m);   // masked -> exp(-inf)=0
    float lsum = (e0 + e1) + (e2 + e3);
    #pragma unroll
    for (int off = 32; off > 0; off >>= 1) lsum += __shfl_xor(lsum, off);
    if ((tid & 63) == 0) redl[tid >> 6] = lsum;
    __syncthreads();
    lsum = redl[0] + redl[1] + redl[2] + redl[3];
    float invl = 1.0f / lsum;
    *(float4*)(row + j0) = make_float4(e0 * invl, e1 * invl, e2 * invl, e3 * invl);
}

// ---------------------------------------------------------------------------
// PV: ctx = (Ph+Pl).vh  (2-product). BM=128, BN=64, BK=64, causal K-limit.
// attn fp32 reg-staged + split into LDS (swizzled writes); v^T hi gload-staged.
// ---------------------------------------------------------------------------
__global__ __launch_bounds__(256, 2)
void k_pv(const float* __restrict__ attn, const ushort* __restrict__ vh,
          ushort* __restrict__ ctxh, ushort* __restrict__ ctxl) {
    const int mt = blockIdx.x, bh = blockIdx.y;
    __shared__ __align__(16) ushort sPh[128 * 64];
    __shared__ __align__(16) ushort sPl[128 * 64];
    __shared__ __align__(16) ushort sVh[64 * 64];
    const int tid = threadIdx.x, w = tid >> 6, l = tid & 63;
    const int wr = w >> 1, wc = w & 1;
    const int lrow = l >> 3, ksrc = ((l & 7) ^ lrow) * 8;
    f32x4 acc[4][2];
    #pragma unroll
    for (int i = 0; i < 4; ++i)
        #pragma unroll
        for (int j = 0; j < 2; ++j) acc[i][j] = (f32x4){0.f, 0.f, 0.f, 0.f};
    const int nsteps = (mt + 1) * 2;
    for (int kt = 0; kt < nsteps; ++kt) {
        __syncthreads();        // protect previous iteration's LDS reads
        #pragma unroll
        for (int j = 0; j < 8; ++j) {
            int idx = j * 256 + tid;           // 0..2047
            int row = idx >> 4, f4 = idx & 15;
            const float* src = attn + ((size_t)bh << 20)
                             + (size_t)(mt * 128 + row) * S_ + kt * 64 + f4 * 4;
            float4 xv = *(const float4*)src;
            ushort h0, h1, h2, h3, l0, l1, l2, l3;
            splitbf(xv.x, h0, l0); splitbf(xv.y, h1, l1);
            splitbf(xv.z, h2, l2); splitbf(xv.w, h3, l3);
            int addr = row * 128 + ((((f4 >> 1) ^ (row & 7))) << 4) + ((f4 & 1) << 3);
            *(ushort4*)((char*)sPh + addr) = make_ushort4(h0, h1, h2, h3);
            *(ushort4*)((char*)sPl + addr) = make_ushort4(l0, l1, l2, l3);
        }
        for (int rr = w; rr < 8; rr += 4) {
            const ushort* g = vh + ((size_t)bh * HD_ + rr * 8 + lrow) * S_
                            + kt * 64 + ksrc;
            GLD16(g, sVh + rr * 512);
        }
        __syncthreads();
        #pragma unroll
        for (int ch = 0; ch < 2; ++ch) {
            const int slot = ch * 4 + (l >> 4);
            bf16x8 ph[4], pl[4], bvh[2];
            #pragma unroll
            for (int mf = 0; mf < 4; ++mf) {
                int row = wr * 64 + mf * 16 + (l & 15);
                ph[mf] = fragld(sPh, row, slot);
                pl[mf] = fragld(sPl, row, slot);
            }
            #pragma unroll
            for (int nf = 0; nf < 2; ++nf)
                bvh[nf] = fragld(sVh, wc * 32 + nf * 16 + (l & 15), slot);
            #pragma unroll
            for (int mf = 0; mf < 4; ++mf)
                #pragma unroll
                for (int nf = 0; nf < 2; ++nf) {
                    acc[mf][nf] = mfma16(ph[mf], bvh[nf], acc[mf][nf]);
                    acc[mf][nf] = mfma16(pl[mf], bvh[nf], acc[mf][nf]);
                }
        }
    }
    const int b = bh / NH_, head = bh - b * NH_;
    #pragma unroll
    for (int mf = 0; mf < 4; ++mf)
        #pragma unroll
        for (int nf = 0; nf < 2; ++nf)
            #pragma unroll
            for (int q = 0; q < 4; ++q) {
                int s = mt * 128 + wr * 64 + mf * 16 + (l >> 4) * 4 + q;
                int d = wc * 32 + nf * 16 + (l & 15);
                size_t idx = ((size_t)(b * S_ + s)) * H_ + head * HD_ + d;
                ushort hv, lv; splitbf(acc[mf][nf][q], hv, lv);
                ctxh[idx] = hv; ctxl[idx] = lv;
            }
}

// ---------------------------------------------------------------------------
extern "C" void kernel_launch(void* const* d_in, const int* in_sizes, int n_in,
                              void* d_out, int out_size, void* d_ws, size_t ws_size,
                              hipStream_t stream) {
    (void)in_sizes; (void)n_in; (void)out_size; (void)ws_size;
    const float* x  = (const float*)d_in[0];
    const float* Wq = (const float*)d_in[1];
    const float* Wk = (const float*)d_in[2];
    const float* Wv = (const float*)d_in[3];
    const float* Wo = (const float*)d_in[4];
    const float* rp = (const float*)d_in[5];

    float* out  = (float*)d_out;
    float* attn = out + (size_t)BB_ * S_ * H_;

    char* p = (char*)d_ws;
    auto alloc = [&](size_t bytes) { char* r = p; p += (bytes + 255) & ~(size_t)255; return r; };
    const size_t NE = (size_t)BB_ * S_ * H_;          // 3,145,728
    float*  Rt   = (float*) alloc(S_ * 12 * 4);
    ushort* xrh  = (ushort*)alloc(NE * 2);            // reused as ctxh after QKV proj
    ushort* xrl  = (ushort*)alloc(NE * 2);            // reused as ctxl
    ushort* Wch  = (ushort*)alloc((size_t)3 * H_ * H_ * 2);
    ushort* Woh  = (ushort*)alloc((size_t)H_ * H_ * 2);
    ushort* qh   = (ushort*)alloc(NE * 2);
    ushort* ql   = (ushort*)alloc(NE * 2);
    ushort* kh   = (ushort*)alloc(NE * 2);
    ushort* vh   = (ushort*)alloc(NE * 2);            // transposed [bh][d][s]
    ushort* ctxh = xrh;     // xr dead after QKV projection (stream-ordered)
    ushort* ctxl = xrl;

    k_se3<<<dim3(4), 256, 0, stream>>>(rp, Rt);
    k_rotate_split<<<dim3(BB_ * S_), 256, 0, stream>>>(x, Rt, xrh, xrl);
    k_wsplit<<<dim3(576, 4), 256, 0, stream>>>(Wq, Wk, Wv, Wo, Wch, Woh);

    // q,k,v projections fused: N = 2304
    k_proj2<4, true><<<dim3(32, 18), 256, 0, stream>>>(
        xrh, xrl, Wch, qh, ql, kh, vh, nullptr);

    k_scores<<<dim3(8, 8, BB_ * NH_), 256, 0, stream>>>(qh, ql, kh, attn);
    k_softmax<<<dim3(S_, BB_ * NH_), 256, 0, stream>>>(attn);
    k_pv<<<dim3(8, BB_ * NH_), 256, 0, stream>>>(attn, vh, ctxh, ctxl);

    // output projection: N = 768
    k_proj2<2, false><<<dim3(32, 12), 256, 0, stream>>>(
        ctxh, ctxl, Woh, nullptr, nullptr, nullptr, nullptr, out);
}

// Round 8
// 394.873 us; speedup vs baseline: 1.8004x; 1.0440x over previous
//
#include <hip/hip_runtime.h>
#include <math.h>

#define S_  1024
#define H_  768
#define NH_ 12
#define HD_ 64
#define BB_ 4

typedef __bf16 bf16x8 __attribute__((ext_vector_type(8)));
typedef float f32x4 __attribute__((ext_vector_type(4)));

// ---- bf16 helpers (RNE, bit-level) -----------------------------------------
__device__ __forceinline__ ushort f2bf(float x) {
    unsigned u = __float_as_uint(x);
    u += 0x7FFF + ((u >> 16) & 1);
    return (ushort)(u >> 16);
}
__device__ __forceinline__ void splitbf(float x, ushort& h, ushort& l) {
    h = f2bf(x);
    float hf = __uint_as_float(((unsigned)h) << 16);
    l = f2bf(x - hf);
}
__device__ __forceinline__ f32x4 mfma16(bf16x8 a, bf16x8 b, f32x4 c) {
    return __builtin_amdgcn_mfma_f32_16x16x32_bf16(a, b, c, 0, 0, 0);
}
#define GLD16(gp, lp) __builtin_amdgcn_global_load_lds( \
    (const __attribute__((address_space(1))) unsigned int*)(gp), \
    (__attribute__((address_space(3))) unsigned int*)(lp), 16, 0, 0)

// XOR-swizzled frag read from a [rows][64] bf16 tile (128B rows, 8 16B slots).
__device__ __forceinline__ bf16x8 fragld(const ushort* tile, int row, int slot) {
    return *(const bf16x8*)((const char*)tile + row * 128 + ((slot ^ (row & 7)) << 4));
}

// ---------------------------------------------------------------------------
// Kernel 1: SE(3) exp map.
// ---------------------------------------------------------------------------
__global__ __launch_bounds__(256)
void k_se3(const float* __restrict__ rp, float* __restrict__ Rt) {
    int s = blockIdx.x * 256 + threadIdx.x;
    if (s >= S_) return;
    float wx = rp[s * 6 + 0], wy = rp[s * 6 + 1], wz = rp[s * 6 + 2];
    float vx = rp[s * 6 + 3], vy = rp[s * 6 + 4], vz = rp[s * 6 + 5];
    float th = sqrtf(wx * wx + wy * wy + wz * wz);
    th = fmaxf(th, 1e-8f);
    float inv = 1.0f / th;
    float ux = wx * inv, uy = wy * inv, uz = wz * inv;
    float K[9] = {0.f, -uz, uy,   uz, 0.f, -ux,   -uy, ux, 0.f};
    float KK[9];
    #pragma unroll
    for (int i = 0; i < 3; ++i)
        #pragma unroll
        for (int j = 0; j < 3; ++j) {
            float acc = 0.f;
            #pragma unroll
            for (int k = 0; k < 3; ++k) acc += K[i * 3 + k] * K[k * 3 + j];
            KK[i * 3 + j] = acc;
        }
    float st = sinf(th), ct = cosf(th);
    float omc = 1.0f - ct;
    float c1 = omc / (th * th);
    float c2 = (th - st) / (th * th * th);
    float R[9], V[9];
    #pragma unroll
    for (int i = 0; i < 9; ++i) {
        float I = (i == 0 || i == 4 || i == 8) ? 1.f : 0.f;
        R[i] = I + st * K[i] + omc * KK[i];
        V[i] = I + c1 * K[i] + c2 * KK[i];
    }
    float tx = V[0] * vx + V[1] * vy + V[2] * vz;
    float ty = V[3] * vx + V[4] * vy + V[5] * vz;
    float tz = V[6] * vx + V[7] * vy + V[8] * vz;
    float* o = Rt + s * 12;
    #pragma unroll
    for (int i = 0; i < 9; ++i) o[i] = R[i];
    o[9] = tx; o[10] = ty; o[11] = tz;
}

// ---------------------------------------------------------------------------
// Kernel 2: rotate + split x into bf16 hi/lo.
// ---------------------------------------------------------------------------
__global__ __launch_bounds__(256)
void k_rotate_split(const float* __restrict__ x, const float* __restrict__ Rt,
                    ushort* __restrict__ xrh, ushort* __restrict__ xrl) {
    __shared__ float sR[12];
    int bs = blockIdx.x;
    int s = bs & (S_ - 1);
    if (threadIdx.x < 12) sR[threadIdx.x] = Rt[s * 12 + threadIdx.x];
    __syncthreads();
    int v = threadIdx.x;
    const float* xp = x + (size_t)bs * H_ + v * 3;
    float x0 = xp[0], x1 = xp[1], x2 = xp[2];
    float y0 = sR[0] * x0 + sR[1] * x1 + sR[2] * x2 + sR[9];
    float y1 = sR[3] * x0 + sR[4] * x1 + sR[5] * x2 + sR[10];
    float y2 = sR[6] * x0 + sR[7] * x1 + sR[8] * x2 + sR[11];
    size_t o = (size_t)bs * H_ + v * 3;
    ushort h, lo;
    splitbf(y0, h, lo); xrh[o + 0] = h; xrl[o + 0] = lo;
    splitbf(y1, h, lo); xrh[o + 1] = h; xrl[o + 1] = lo;
    splitbf(y2, h, lo); xrh[o + 2] = h; xrl[o + 2] = lo;
}

// ---------------------------------------------------------------------------
// Kernel 3: round weights to bf16 HI only.
// ---------------------------------------------------------------------------
__global__ __launch_bounds__(256)
void k_wsplit(const float* __restrict__ Wq, const float* __restrict__ Wk,
              const float* __restrict__ Wv, const float* __restrict__ Wo,
              ushort* __restrict__ Wch, ushort* __restrict__ Woh) {
    const int wsel = blockIdx.y;
    const float* src = (wsel == 0) ? Wq : (wsel == 1) ? Wk : (wsel == 2) ? Wv : Wo;
    const int e = (blockIdx.x * 256 + threadIdx.x) * 4;
    float4 xv = *(const float4*)(src + e);
    ushort4 hv = make_ushort4(f2bf(xv.x), f2bf(xv.y), f2bf(xv.z), f2bf(xv.w));
    if (wsel < 3) *(ushort4*)(Wch + (size_t)wsel * (H_ * H_) + e) = hv;
    else          *(ushort4*)(Woh + e) = hv;
}

// ---------------------------------------------------------------------------
// 2-product split GEMM: C = (Ah+Al) . Bh^T, fp32 accum.
// QKV: epilogue -> q split hi/lo, k hi, V TRANSPOSED [bh][d][s] hi.
// OUT: epilogue -> fp32 d_out.
// ---------------------------------------------------------------------------
template<int NF, bool QKV>
__global__ __launch_bounds__(256, 2)
void k_proj2(const ushort* __restrict__ Ah, const ushort* __restrict__ Al,
             const ushort* __restrict__ Bh,
             ushort* __restrict__ qh, ushort* __restrict__ ql,
             ushort* __restrict__ kh, ushort* __restrict__ vh,
             float* __restrict__ outp) {
    constexpr int BN = NF * 32;
    constexpr int TOT = 32 + BN / 8;
    __shared__ __align__(16) ushort sAh[128 * 64];
    __shared__ __align__(16) ushort sAl[128 * 64];
    __shared__ __align__(16) ushort sBh[BN * 64];
    const int mt = blockIdx.x, nt = blockIdx.y;
    const int tid = threadIdx.x, w = tid >> 6, l = tid & 63;
    const int wr = w >> 1, wc = w & 1;
    const int lrow = l >> 3;
    const int ksrc = ((l & 7) ^ lrow) * 8;

    f32x4 acc[4][NF];
    #pragma unroll
    for (int i = 0; i < 4; ++i)
        #pragma unroll
        for (int j = 0; j < NF; ++j) acc[i][j] = (f32x4){0.f, 0.f, 0.f, 0.f};

    for (int kt = 0; kt < H_ / 64; ++kt) {
        const int k0 = kt * 64;
        for (int rr = w; rr < TOT; rr += 4) {
            int t = (rr < 16) ? 0 : (rr < 32) ? 1 : 2;
            int r = rr - ((rr < 16) ? 0 : (rr < 32) ? 16 : 32);
            const ushort* src = (t == 0) ? Ah : (t == 1) ? Al : Bh;
            size_t rowb = (t < 2) ? (size_t)mt * 128 : (size_t)nt * BN;
            const ushort* g = src + (rowb + r * 8 + lrow) * H_ + k0 + ksrc;
            ushort* dstt = (t == 0) ? sAh : (t == 1) ? sAl : sBh;
            GLD16(g, dstt + r * 512);
        }
        __syncthreads();
        #pragma unroll
        for (int ch = 0; ch < 2; ++ch) {
            const int slot = ch * 4 + (l >> 4);
            bf16x8 ah[4], al[4], bh[NF];
            #pragma unroll
            for (int mf = 0; mf < 4; ++mf) {
                int row = wr * 64 + mf * 16 + (l & 15);
                ah[mf] = fragld(sAh, row, slot);
                al[mf] = fragld(sAl, row, slot);
            }
            #pragma unroll
            for (int nf = 0; nf < NF; ++nf)
                bh[nf] = fragld(sBh, wc * (NF * 16) + nf * 16 + (l & 15), slot);
            #pragma unroll
            for (int mf = 0; mf < 4; ++mf)
                #pragma unroll
                for (int nf = 0; nf < NF; ++nf) {
                    acc[mf][nf] = mfma16(ah[mf], bh[nf], acc[mf][nf]);
                    acc[mf][nf] = mfma16(al[mf], bh[nf], acc[mf][nf]);
                }
        }
        __syncthreads();
    }
    #pragma unroll
    for (int mf = 0; mf < 4; ++mf)
        #pragma unroll
        for (int nf = 0; nf < NF; ++nf)
            #pragma unroll
            for (int q = 0; q < 4; ++q) {
                float val = acc[mf][nf][q];
                int row = mt * 128 + wr * 64 + mf * 16 + (l >> 4) * 4 + q;
                int col = nt * BN + wc * (NF * 16) + nf * 16 + (l & 15);
                if constexpr (QKV) {
                    int which = col / H_;
                    int rem = col - which * H_;
                    int hh = rem >> 6, d = rem & 63;
                    int b = row >> 10, s = row & (S_ - 1);
                    if (which == 2) {
                        vh[((size_t)(b * NH_ + hh) * HD_ + d) * S_ + s] = f2bf(val);
                    } else if (which == 1) {
                        kh[(((size_t)(b * NH_ + hh) * S_ + s) << 6) + d] = f2bf(val);
                    } else {
                        size_t idx = (((size_t)(b * NH_ + hh) * S_ + s) << 6) + d;
                        ushort hv, lv; splitbf(val, hv, lv);
                        qh[idx] = hv; ql[idx] = lv;
                    }
                } else {
                    outp[(size_t)row * H_ + col] = val;
                }
            }
}

// ---------------------------------------------------------------------------
// Pass A (stats): per (mt,bh) 128-row block, online per-row softmax stats
// (m, 1/l) over causal cols. q hi/lo in registers; K hi staged in LDS.
// Wave w owns rows w*32..w*32+31. No attn traffic.
// ---------------------------------------------------------------------------
__global__ __launch_bounds__(256, 2)
void k_stats(const ushort* __restrict__ qh, const ushort* __restrict__ ql,
             const ushort* __restrict__ kh, float2* __restrict__ stats) {
    const int mt = blockIdx.x, bh = blockIdx.y;
    __shared__ __align__(16) ushort sK[64 * 64];
    const int tid = threadIdx.x, w = tid >> 6, l = tid & 63;
    const int lrow = l >> 3, ksrc = ((l & 7) ^ lrow) * 8;
    const int qrow = mt * 128 + w * 32;
    bf16x8 qf[2][2][2];
    #pragma unroll
    for (int mf = 0; mf < 2; ++mf)
        #pragma unroll
        for (int kc = 0; kc < 2; ++kc) {
            int row = qrow + mf * 16 + (l & 15);
            size_t off = (((size_t)bh * S_ + row) << 6) + (kc * 4 + (l >> 4)) * 8;
            qf[mf][kc][0] = *(const bf16x8*)(qh + off);
            qf[mf][kc][1] = *(const bf16x8*)(ql + off);
        }
    float m_r[2][4], l_r[2][4];
    #pragma unroll
    for (int mf = 0; mf < 2; ++mf)
        #pragma unroll
        for (int q_ = 0; q_ < 4; ++q_) { m_r[mf][q_] = -INFINITY; l_r[mf][q_] = 0.f; }

    const int nkt = 2 * mt + 2;
    for (int kt = 0; kt < nkt; ++kt) {
        __syncthreads();
        for (int rr = w; rr < 8; rr += 4)
            GLD16(kh + (((size_t)bh * S_ + kt * 64 + rr * 8 + lrow) << 6) + ksrc,
                  sK + rr * 512);
        __syncthreads();
        f32x4 accs[2][4];
        #pragma unroll
        for (int i = 0; i < 2; ++i)
            #pragma unroll
            for (int j = 0; j < 4; ++j) accs[i][j] = (f32x4){0.f, 0.f, 0.f, 0.f};
        #pragma unroll
        for (int kc = 0; kc < 2; ++kc) {
            int slot = kc * 4 + (l >> 4);
            bf16x8 kb[4];
            #pragma unroll
            for (int nf = 0; nf < 4; ++nf)
                kb[nf] = fragld(sK, nf * 16 + (l & 15), slot);
            #pragma unroll
            for (int mf = 0; mf < 2; ++mf)
                #pragma unroll
                for (int nf = 0; nf < 4; ++nf) {
                    accs[mf][nf] = mfma16(qf[mf][kc][0], kb[nf], accs[mf][nf]);
                    accs[mf][nf] = mfma16(qf[mf][kc][1], kb[nf], accs[mf][nf]);
                }
        }
        #pragma unroll
        for (int mf = 0; mf < 2; ++mf)
            #pragma unroll
            for (int q_ = 0; q_ < 4; ++q_) {
                int R = qrow + mf * 16 + (l >> 4) * 4 + q_;
                float tmp[4]; float tmax = -INFINITY;
                #pragma unroll
                for (int nf = 0; nf < 4; ++nf) {
                    int j = kt * 64 + nf * 16 + (l & 15);
                    float xx = accs[mf][nf][q_] * 0.125f;
                    tmp[nf] = (j <= R) ? xx : -INFINITY;
                    tmax = fmaxf(tmax, tmp[nf]);
                }
                #pragma unroll
                for (int off = 1; off < 16; off <<= 1)
                    tmax = fmaxf(tmax, __shfl_xor(tmax, off));
                float mo = m_r[mf][q_];
                float mn = fmaxf(mo, tmax);
                float ts = 0.f;
                #pragma unroll
                for (int nf = 0; nf < 4; ++nf) ts += __expf(tmp[nf] - mn);
                #pragma unroll
                for (int off = 1; off < 16; off <<= 1) ts += __shfl_xor(ts, off);
                l_r[mf][q_] = l_r[mf][q_] * __expf(mo - mn) + ts;
                m_r[mf][q_] = mn;
            }
    }
    if ((l & 15) == 0) {
        #pragma unroll
        for (int mf = 0; mf < 2; ++mf)
            #pragma unroll
            for (int q_ = 0; q_ < 4; ++q_) {
                int R = qrow + mf * 16 + (l >> 4) * 4 + q_;
                stats[(size_t)bh * S_ + R] =
                    make_float2(m_r[mf][q_], 1.0f / l_r[mf][q_]);
            }
    }
}

// ---------------------------------------------------------------------------
// Pass B (fused): recompute QK^T (identical op order to k_stats), normalize
// with (m, invl), write attn exactly once (incl. zero upper triangle), and
// accumulate PV via wave-private swizzled P-LDS (P hi-only). ctx -> hi/lo.
// LDS: sQP 32KB (q staging; first 16KB reused as 4x4KB wave-private P tiles),
// sK 8KB, sVt 8KB -> 48KB total, 3 blocks/CU.
// ---------------------------------------------------------------------------
__global__ __launch_bounds__(256, 2)
void k_fused(const ushort* __restrict__ qh, const ushort* __restrict__ ql,
             const ushort* __restrict__ kh, const ushort* __restrict__ vT,
             const float2* __restrict__ stats, float* __restrict__ attn,
             ushort* __restrict__ ctxh, ushort* __restrict__ ctxl) {
    const int mt = blockIdx.x, bh = blockIdx.y;
    __shared__ __align__(16) ushort sQP[16384];     // 32 KB
    __shared__ __align__(16) ushort sK[64 * 64];    // 8 KB
    __shared__ __align__(16) ushort sVt[64 * 64];   // 8 KB
    const int tid = threadIdx.x, w = tid >> 6, l = tid & 63;
    const int lrow = l >> 3, ksrc = ((l & 7) ^ lrow) * 8;
    const size_t abase = (size_t)bh << 20;

    // stage q hi/lo [128][64]
    for (int rr = w; rr < 32; rr += 4) {
        int t = rr >> 4, r = rr & 15;
        const ushort* src = t ? ql : qh;
        GLD16(src + (((size_t)bh * S_ + mt * 128 + r * 8 + lrow) << 6) + ksrc,
              sQP + t * 8192 + r * 512);
    }
    __syncthreads();
    bf16x8 qf[2][2][2];
    #pragma unroll
    for (int mf = 0; mf < 2; ++mf)
        #pragma unroll
        for (int kc = 0; kc < 2; ++kc) {
            int row = w * 32 + mf * 16 + (l & 15);
            int slot = kc * 4 + (l >> 4);
            qf[mf][kc][0] = fragld(sQP, row, slot);
            qf[mf][kc][1] = fragld(sQP + 8192, row, slot);
        }
    float stm[2][4], stl[2][4];
    #pragma unroll
    for (int mf = 0; mf < 2; ++mf)
        #pragma unroll
        for (int q_ = 0; q_ < 4; ++q_) {
            int R = mt * 128 + w * 32 + mf * 16 + (l >> 4) * 4 + q_;
            float2 st = stats[(size_t)bh * S_ + R];
            stm[mf][q_] = st.x; stl[mf][q_] = st.y;
        }
    f32x4 ctx[2][4];
    #pragma unroll
    for (int i = 0; i < 2; ++i)
        #pragma unroll
        for (int j = 0; j < 4; ++j) ctx[i][j] = (f32x4){0.f, 0.f, 0.f, 0.f};
    ushort* sPw = sQP + w * 2048;                  // wave-private [32][64]

    const int nkt = 2 * mt + 2;
    for (int kt = 0; kt < nkt; ++kt) {
        __syncthreads();   // prior iter's sK/sVt reads done (also q reads, iter 0)
        for (int rr = w; rr < 8; rr += 4)
            GLD16(kh + (((size_t)bh * S_ + kt * 64 + rr * 8 + lrow) << 6) + ksrc,
                  sK + rr * 512);
        for (int rr = w; rr < 8; rr += 4)
            GLD16(vT + (((size_t)bh * HD_ + rr * 8 + lrow) << 10) + kt * 64 + ksrc,
                  sVt + rr * 512);
        __syncthreads();
        f32x4 accs[2][4];
        #pragma unroll
        for (int i = 0; i < 2; ++i)
            #pragma unroll
            for (int j = 0; j < 4; ++j) accs[i][j] = (f32x4){0.f, 0.f, 0.f, 0.f};
        #pragma unroll
        for (int kc = 0; kc < 2; ++kc) {
            int slot = kc * 4 + (l >> 4);
            bf16x8 kb[4];
            #pragma unroll
            for (int nf = 0; nf < 4; ++nf)
                kb[nf] = fragld(sK, nf * 16 + (l & 15), slot);
            #pragma unroll
            for (int mf = 0; mf < 2; ++mf)
                #pragma unroll
                for (int nf = 0; nf < 4; ++nf) {
                    accs[mf][nf] = mfma16(qf[mf][kc][0], kb[nf], accs[mf][nf]);
                    accs[mf][nf] = mfma16(qf[mf][kc][1], kb[nf], accs[mf][nf]);
                }
        }
        // P = exp(S*scale - m) * invl ; write attn; write P-hi to wave LDS
        #pragma unroll
        for (int mf = 0; mf < 2; ++mf)
            #pragma unroll
            for (int nf = 0; nf < 4; ++nf)
                #pragma unroll
                for (int q_ = 0; q_ < 4; ++q_) {
                    int rl = mf * 16 + (l >> 4) * 4 + q_;
                    int R  = mt * 128 + w * 32 + rl;
                    int j  = kt * 64 + nf * 16 + (l & 15);
                    float xx = accs[mf][nf][q_] * 0.125f;
                    float p = (j <= R) ? __expf(xx - stm[mf][q_]) * stl[mf][q_] : 0.f;
                    attn[abase + ((size_t)R << 10) + j] = p;
                    int col = nf * 16 + (l & 15);
                    int a = rl * 128 + ((((col >> 3) ^ (rl & 7))) << 4) + ((col & 7) << 1);
                    *(ushort*)((char*)sPw + a) = f2bf(p);
                }
        // PV: ctx += P . V   (A = P [32 rows][kv], B = V^T [d][kv])
        #pragma unroll
        for (int kc = 0; kc < 2; ++kc) {
            int slot = kc * 4 + (l >> 4);
            bf16x8 pf[2], vb[4];
            #pragma unroll
            for (int mf = 0; mf < 2; ++mf)
                pf[mf] = fragld(sPw, mf * 16 + (l & 15), slot);
            #pragma unroll
            for (int nd = 0; nd < 4; ++nd)
                vb[nd] = fragld(sVt, nd * 16 + (l & 15), slot);
            #pragma unroll
            for (int mf = 0; mf < 2; ++mf)
                #pragma unroll
                for (int nd = 0; nd < 4; ++nd)
                    ctx[mf][nd] = mfma16(pf[mf], vb[nd], ctx[mf][nd]);
        }
    }
    // zero-fill upper-triangle tiles (cols >= (mt+1)*128)
    const int c0 = (mt + 1) * 128;
    const float4 z4 = make_float4(0.f, 0.f, 0.f, 0.f);
    for (int r = w; r < 128; r += 4) {
        size_t rb = abase + ((size_t)(mt * 128 + r) << 10);
        for (int c = c0 + l * 4; c < S_; c += 256)
            *(float4*)(attn + rb + c) = z4;
    }
    // ctx epilogue -> hi/lo row-major [4096][768]
    const int b = bh / NH_, head = bh - b * NH_;
    #pragma unroll
    for (int mf = 0; mf < 2; ++mf)
        #pragma unroll
        for (int nd = 0; nd < 4; ++nd)
            #pragma unroll
            for (int q_ = 0; q_ < 4; ++q_) {
                int s = mt * 128 + w * 32 + mf * 16 + (l >> 4) * 4 + q_;
                int d = nd * 16 + (l & 15);
                size_t idx = ((size_t)(b * S_ + s)) * H_ + head * HD_ + d;
                ushort hv, lv; splitbf(ctx[mf][nd][q_], hv, lv);
                ctxh[idx] = hv; ctxl[idx] = lv;
            }
}

// ---------------------------------------------------------------------------
extern "C" void kernel_launch(void* const* d_in, const int* in_sizes, int n_in,
                              void* d_out, int out_size, void* d_ws, size_t ws_size,
                              hipStream_t stream) {
    (void)in_sizes; (void)n_in; (void)out_size; (void)ws_size;
    const float* x  = (const float*)d_in[0];
    const float* Wq = (const float*)d_in[1];
    const float* Wk = (const float*)d_in[2];
    const float* Wv = (const float*)d_in[3];
    const float* Wo = (const float*)d_in[4];
    const float* rp = (const float*)d_in[5];

    float* out  = (float*)d_out;
    float* attn = out + (size_t)BB_ * S_ * H_;

    char* p = (char*)d_ws;
    auto alloc = [&](size_t bytes) { char* r = p; p += (bytes + 255) & ~(size_t)255; return r; };
    const size_t NE = (size_t)BB_ * S_ * H_;
    float*  Rt    = (float*) alloc(S_ * 12 * 4);
    ushort* xrh   = (ushort*)alloc(NE * 2);           // reused as ctxh
    ushort* xrl   = (ushort*)alloc(NE * 2);           // reused as ctxl
    ushort* Wch   = (ushort*)alloc((size_t)3 * H_ * H_ * 2);
    ushort* Woh   = (ushort*)alloc((size_t)H_ * H_ * 2);
    ushort* qh    = (ushort*)alloc(NE * 2);
    ushort* ql    = (ushort*)alloc(NE * 2);
    ushort* kh    = (ushort*)alloc(NE * 2);
    ushort* vh    = (ushort*)alloc(NE * 2);           // transposed [bh][d][s]
    float2* stats = (float2*)alloc((size_t)BB_ * NH_ * S_ * 8);
    ushort* ctxh  = xrh;
    ushort* ctxl  = xrl;

    k_se3<<<dim3(4), 256, 0, stream>>>(rp, Rt);
    k_rotate_split<<<dim3(BB_ * S_), 256, 0, stream>>>(x, Rt, xrh, xrl);
    k_wsplit<<<dim3(576, 4), 256, 0, stream>>>(Wq, Wk, Wv, Wo, Wch, Woh);

    k_proj2<4, true><<<dim3(32, 18), 256, 0, stream>>>(
        xrh, xrl, Wch, qh, ql, kh, vh, nullptr);

    k_stats<<<dim3(8, BB_ * NH_), 256, 0, stream>>>(qh, ql, kh, stats);
    k_fused<<<dim3(8, BB_ * NH_), 256, 0, stream>>>(qh, ql, kh, vh, stats,
                                                    attn, ctxh, ctxl);

    k_proj2<2, false><<<dim3(32, 12), 256, 0, stream>>>(
        ctxh, ctxl, Woh, nullptr, nullptr, nullptr, nullptr, out);
}